// Round 7
// baseline (1090.770 us; speedup 1.0000x reference)
//
#include <hip/hip_runtime.h>
#include <stdint.h>

typedef __attribute__((ext_vector_type(8))) short short8;
typedef __attribute__((ext_vector_type(4))) float floatx4;
typedef __attribute__((ext_vector_type(2))) uint32_t u32x2;
typedef __attribute__((ext_vector_type(4))) uint32_t u32x4;

#define Hh 384
#define Ww 384
#define Cc 11
#define Nn 32
#define PITCH 72  // 64 + 8 pad bf16 elems; 144 B rows: 16B-aligned

__device__ __forceinline__ float bf2f(unsigned short b) {
  union { uint32_t u; float f; } z; z.u = ((uint32_t)b) << 16;
  return z.f;
}
// (bf16_trunc(hi) << 16) | bf16_trunc(lo) in one v_perm_b32.
__device__ __forceinline__ uint32_t pkbf(float hi, float lo) {
  union { float f; uint32_t u; } a, b; a.f = hi; b.f = lo;
  return __builtin_amdgcn_perm(a.u, b.u, 0x07060302u);
}

// lgkm-only barrier: LDS ordered; global loads/stores stay in flight.
#define BAR() do {                                          \
    asm volatile("s_waitcnt lgkmcnt(0)" ::: "memory");      \
    __builtin_amdgcn_s_barrier();                           \
    asm volatile("" ::: "memory");                          \
  } while (0)

// ---------------------------------------------------------------------------
// Split kernel: each block does a 64x64 tile for HALF the channels (6 or 5),
// producing partial online-softmax (m,s). Lean registers (no prefetch window,
// transient stage regs <=16) + __launch_bounds__(256,6) -> ~6 resident
// blocks/CU (2x the previous ~3). Last finisher of each pair merges in-kernel.
// ---------------------------------------------------------------------------
__global__ __launch_bounds__(256, 6)
void center_split(const float* __restrict__ X, const float* __restrict__ Cen,
                  const int* __restrict__ Lab, float* __restrict__ Out,
                  float2* __restrict__ Ws, int* __restrict__ Flags) {
  __shared__ __align__(16) unsigned short Alds[64 * PITCH];  // A[i][k]  (x rows)
  __shared__ __align__(16) unsigned short Blds[64 * PITCH];  // Bt[j][k] (centers cols)
  __shared__ float red[4];
  __shared__ int oldsh;

  const int bx    = blockIdx.x;
  const int chunk = (bx >= 1152) ? 1 : 0;   // 1152 % 8 == 0: keeps XCD map
  const int bxl   = bx - chunk * 1152;
  const int c0    = chunk * 6;
  const int NT    = chunk ? 30 : 36;        // (5 or 6 channels) * 6 k-tiles

  // XCD swizzle: all 36 blocks of one n (both chunks) share an XCD.
  const int xcd  = bxl & 7;
  const int slot = bxl >> 3;
  const int grp  = slot / 36;
  const int t36  = slot - grp * 36;
  const int n    = xcd + (grp << 3);
  const int ib = t36 / 6;
  const int jb = t36 - ib * 6;
  const int i0 = ib << 6, j0 = jb << 6;

  const int t   = threadIdx.x;
  const int l   = t & 63;
  const int w   = t >> 6;
  const int wr  = (w >> 1) << 5;
  const int wc  = (w & 1) << 5;
  const int q4  = l >> 4;
  const int l16 = l & 15;
  const int sa  = t & 15;            // A staging: col segment
  const int sr  = t >> 4;            // A staging: row base

  const size_t plane = (size_t)Hh * Ww;
  const float* xbase = X   + ((size_t)n * Cc + c0) * plane;
  const float* cbase = Cen + ((size_t)n * Cc + c0) * plane;
  const size_t aoffg = (size_t)(i0 + sr) * Ww + (sa << 2);

  float m[16], s[16];
#pragma unroll
  for (int i = 0; i < 16; ++i) { m[i] = -3.0e38f; s[i] = 0.0f; }

  floatx4 acc[2][2];
#pragma unroll
  for (int a = 0; a < 2; ++a)
#pragma unroll
    for (int b = 0; b < 2; ++b) acc[a][b] = (floatx4){0.f, 0.f, 0.f, 0.f};

  int kb = 0, c = 0;
  for (int it = 0; it < NT; ++it) {
    BAR();   // previous iteration's LDS reads complete

    // ---- stage A (current tile) : 16 transient regs ----
    {
      const float* ap = xbase + (size_t)c * plane + (kb << 6) + aoffg;
      float4 a0 = *reinterpret_cast<const float4*>(ap);
      float4 a1 = *reinterpret_cast<const float4*>(ap + (size_t)16 * Ww);
      float4 a2 = *reinterpret_cast<const float4*>(ap + (size_t)32 * Ww);
      float4 a3 = *reinterpret_cast<const float4*>(ap + (size_t)48 * Ww);
      u32x2 p0, p1, p2, p3;
      p0.x = pkbf(a0.y, a0.x); p0.y = pkbf(a0.w, a0.z);
      p1.x = pkbf(a1.y, a1.x); p1.y = pkbf(a1.w, a1.z);
      p2.x = pkbf(a2.y, a2.x); p2.y = pkbf(a2.w, a2.z);
      p3.x = pkbf(a3.y, a3.x); p3.y = pkbf(a3.w, a3.z);
      *reinterpret_cast<u32x2*>(&Alds[(sr +  0) * PITCH + (sa << 2)]) = p0;
      *reinterpret_cast<u32x2*>(&Alds[(sr + 16) * PITCH + (sa << 2)]) = p1;
      *reinterpret_cast<u32x2*>(&Alds[(sr + 32) * PITCH + (sa << 2)]) = p2;
      *reinterpret_cast<u32x2*>(&Alds[(sr + 48) * PITCH + (sa << 2)]) = p3;
    }
    // ---- stage B in two 8-reg gulps ----
#pragma unroll
    for (int p = 0; p < 2; ++p) {
      const int kbase = (w << 3) + (p << 5);
      const float* bp = cbase + (size_t)c * plane +
                        (size_t)((kb << 6) + kbase) * Ww + j0 + l;
      float b0 = bp[0];
      float b1 = bp[(size_t)1 * Ww];
      float b2 = bp[(size_t)2 * Ww];
      float b3 = bp[(size_t)3 * Ww];
      float b4 = bp[(size_t)4 * Ww];
      float b5 = bp[(size_t)5 * Ww];
      float b6 = bp[(size_t)6 * Ww];
      float b7 = bp[(size_t)7 * Ww];
      u32x4 pk;
      pk.x = pkbf(b1, b0); pk.y = pkbf(b3, b2);
      pk.z = pkbf(b5, b4); pk.w = pkbf(b7, b6);
      *reinterpret_cast<u32x4*>(&Blds[l * PITCH + kbase]) = pk;
    }

    BAR();   // LDS writes visible

    // ---- epilogue-term fold: acc -= 0.5*(x^2 or c^2); res = -2*acc ----
    if (kb == jb) {    // A tile cols are j0..j0+63
#pragma unroll
      for (int fr = 0; fr < 2; ++fr)
#pragma unroll
        for (int fc = 0; fc < 2; ++fc)
#pragma unroll
          for (int r = 0; r < 4; ++r) {
            const int pr = wr + (fr << 4) + (q4 << 2) + r;
            const int pc = wc + (fc << 4) + l16;
            float xv = bf2f(Alds[pr * PITCH + pc]);
            acc[fr][fc][r] -= 0.5f * xv * xv;
          }
    }
    if (kb == ib) {    // Bt tile k-range is i0..i0+63
#pragma unroll
      for (int fr = 0; fr < 2; ++fr)
#pragma unroll
        for (int fc = 0; fc < 2; ++fc)
#pragma unroll
          for (int r = 0; r < 4; ++r) {
            const int pr = wr + (fr << 4) + (q4 << 2) + r;
            const int pc = wc + (fc << 4) + l16;
            float cv = bf2f(Blds[pc * PITCH + pr]);
            acc[fr][fc][r] -= 0.5f * cv * cv;
          }
    }

    // ---- MFMA: 2 k-steps of 32 ----
#pragma unroll
    for (int ks = 0; ks < 2; ++ks) {
      const int ko = (ks << 5) + (q4 << 3);
      short8 a0 = *reinterpret_cast<const short8*>(&Alds[(wr +      l16) * PITCH + ko]);
      short8 a1 = *reinterpret_cast<const short8*>(&Alds[(wr + 16 + l16) * PITCH + ko]);
      short8 b0 = *reinterpret_cast<const short8*>(&Blds[(wc +      l16) * PITCH + ko]);
      short8 b1 = *reinterpret_cast<const short8*>(&Blds[(wc + 16 + l16) * PITCH + ko]);
      acc[0][0] = __builtin_amdgcn_mfma_f32_16x16x32_bf16(a0, b0, acc[0][0], 0, 0, 0);
      acc[0][1] = __builtin_amdgcn_mfma_f32_16x16x32_bf16(a0, b1, acc[0][1], 0, 0, 0);
      acc[1][0] = __builtin_amdgcn_mfma_f32_16x16x32_bf16(a1, b0, acc[1][0], 0, 0, 0);
      acc[1][1] = __builtin_amdgcn_mfma_f32_16x16x32_bf16(a1, b1, acc[1][1], 0, 0, 0);
    }

    // ---- channel boundary: online softmax update ----
    if (kb == 5) {
#pragma unroll
      for (int fr = 0; fr < 2; ++fr)
#pragma unroll
        for (int fc = 0; fc < 2; ++fc)
#pragma unroll
          for (int r = 0; r < 4; ++r) {
            const int idx = ((fr << 1) + fc) * 4 + r;
            float res = -2.0f * acc[fr][fc][r];
            float mi = m[idx];
            if (res <= mi) {
              s[idx] += __expf(res - mi);
            } else {
              s[idx] = s[idx] * __expf(mi - res) + 1.0f;
              m[idx] = res;
            }
            acc[fr][fc][r] = 0.0f;
          }
    }

    ++kb; if (kb == 6) { kb = 0; ++c; }
  }

  // ---- write partial (m, s) ----
  float2* wsk = Ws + ((size_t)chunk * Nn + n) * plane;
#pragma unroll
  for (int fr = 0; fr < 2; ++fr)
#pragma unroll
    for (int fc = 0; fc < 2; ++fc)
#pragma unroll
      for (int r = 0; r < 4; ++r) {
        const int idx = ((fr << 1) + fc) * 4 + r;
        const int pr = i0 + wr + (fr << 4) + (q4 << 2) + r;
        const int pc = j0 + wc + (fc << 4) + l16;
        float2 v; v.x = m[idx]; v.y = s[idx];
        wsk[(size_t)pr * Ww + pc] = v;
      }

  // ---- pair handshake: last finisher merges this tile ----
  __syncthreads();     // drains vmcnt(0): ws stores complete (in L2)
  __threadfence();     // release
  if (t == 0) oldsh = atomicAdd(&Flags[n * 36 + t36], 1);
  __syncthreads();
  if (oldsh == 1) {
    __threadfence();   // acquire
    const float2* w0 = Ws + (size_t)n * plane;
    const float2* w1 = Ws + (size_t)(Nn + n) * plane;
    const int*    lb = Lab + (size_t)n * plane;
    float local = 0.0f;
#pragma unroll
    for (int u = 0; u < 16; ++u) {
      const int idx = (u << 8) + t;                  // 0..4095
      const size_t g = (size_t)(i0 + (idx >> 6)) * Ww + (j0 + (idx & 63));
      float2 a = w0[g], b = w1[g];
      float S;
      if (a.x >= b.x) S = a.y + b.y * __expf(b.x - a.x);
      else            S = b.y + a.y * __expf(a.x - b.x);
      float d = (1.0f / S) * (float)lb[g];
      d = fminf(fmaxf(d, 1e-12f), 1e12f);
      local += d;
    }
#pragma unroll
    for (int off = 32; off > 0; off >>= 1) local += __shfl_down(local, off, 64);
    if (l == 0) red[w] = local;
    __syncthreads();
    if (t == 0)
      atomicAdd(Out, (red[0] + red[1] + red[2] + red[3]) * (1.0f / 4718592.0f));
  }
}

// ---------------------------------------------------------------------------
// Fallback (no workspace): round-6 monolithic kernel, 211 us steady.
// ---------------------------------------------------------------------------
__global__ __launch_bounds__(256, 3)
void center_mono(const float* __restrict__ X, const float* __restrict__ Cen,
                 const int* __restrict__ Lab, float* __restrict__ Out) {
  __shared__ __align__(16) unsigned short Alds[64 * PITCH];
  __shared__ __align__(16) unsigned short Blds[64 * PITCH];
  __shared__ float red[4];

  const int bx   = blockIdx.x;
  const int xcd  = bx & 7;
  const int slot = bx >> 3;
  const int grp  = slot / 36;
  const int t36  = slot - grp * 36;
  const int n    = xcd + (grp << 3);
  const int ib = t36 / 6;
  const int jb = t36 - ib * 6;
  const int i0 = ib << 6, j0 = jb << 6;

  const int t   = threadIdx.x;
  const int l   = t & 63;
  const int w   = t >> 6;
  const int wr  = (w >> 1) << 5;
  const int wc  = (w & 1) << 5;
  const int q4  = l >> 4;
  const int l16 = l & 15;
  const int sa  = t & 15;
  const int sr  = t >> 4;

  const size_t plane = (size_t)Hh * Ww;
  const float* xbase = X   + (size_t)n * Cc * plane;
  const float* cbase = Cen + (size_t)n * Cc * plane;
  const size_t aoffg = (size_t)(i0 + sr) * Ww + (sa << 2);

  float m[16], s[16];
#pragma unroll
  for (int i = 0; i < 16; ++i) { m[i] = -3.0e38f; s[i] = 0.0f; }
  floatx4 acc[2][2];
#pragma unroll
  for (int a = 0; a < 2; ++a)
#pragma unroll
    for (int b = 0; b < 2; ++b) acc[a][b] = (floatx4){0.f, 0.f, 0.f, 0.f};

  int kb = 0, c = 0;
  for (int it = 0; it < 66; ++it) {
    BAR();
    {
      const float* ap = xbase + (size_t)c * plane + (kb << 6) + aoffg;
      float4 a0 = *reinterpret_cast<const float4*>(ap);
      float4 a1 = *reinterpret_cast<const float4*>(ap + (size_t)16 * Ww);
      float4 a2 = *reinterpret_cast<const float4*>(ap + (size_t)32 * Ww);
      float4 a3 = *reinterpret_cast<const float4*>(ap + (size_t)48 * Ww);
      u32x2 p0, p1, p2, p3;
      p0.x = pkbf(a0.y, a0.x); p0.y = pkbf(a0.w, a0.z);
      p1.x = pkbf(a1.y, a1.x); p1.y = pkbf(a1.w, a1.z);
      p2.x = pkbf(a2.y, a2.x); p2.y = pkbf(a2.w, a2.z);
      p3.x = pkbf(a3.y, a3.x); p3.y = pkbf(a3.w, a3.z);
      *reinterpret_cast<u32x2*>(&Alds[(sr +  0) * PITCH + (sa << 2)]) = p0;
      *reinterpret_cast<u32x2*>(&Alds[(sr + 16) * PITCH + (sa << 2)]) = p1;
      *reinterpret_cast<u32x2*>(&Alds[(sr + 32) * PITCH + (sa << 2)]) = p2;
      *reinterpret_cast<u32x2*>(&Alds[(sr + 48) * PITCH + (sa << 2)]) = p3;
    }
#pragma unroll
    for (int p = 0; p < 2; ++p) {
      const int kbase = (w << 3) + (p << 5);
      const float* bp = cbase + (size_t)c * plane +
                        (size_t)((kb << 6) + kbase) * Ww + j0 + l;
      float b0 = bp[0];
      float b1 = bp[(size_t)1 * Ww];
      float b2 = bp[(size_t)2 * Ww];
      float b3 = bp[(size_t)3 * Ww];
      float b4 = bp[(size_t)4 * Ww];
      float b5 = bp[(size_t)5 * Ww];
      float b6 = bp[(size_t)6 * Ww];
      float b7 = bp[(size_t)7 * Ww];
      u32x4 pk;
      pk.x = pkbf(b1, b0); pk.y = pkbf(b3, b2);
      pk.z = pkbf(b5, b4); pk.w = pkbf(b7, b6);
      *reinterpret_cast<u32x4*>(&Blds[l * PITCH + kbase]) = pk;
    }
    BAR();
    if (kb == jb) {
#pragma unroll
      for (int fr = 0; fr < 2; ++fr)
#pragma unroll
        for (int fc = 0; fc < 2; ++fc)
#pragma unroll
          for (int r = 0; r < 4; ++r) {
            const int pr = wr + (fr << 4) + (q4 << 2) + r;
            const int pc = wc + (fc << 4) + l16;
            float xv = bf2f(Alds[pr * PITCH + pc]);
            acc[fr][fc][r] -= 0.5f * xv * xv;
          }
    }
    if (kb == ib) {
#pragma unroll
      for (int fr = 0; fr < 2; ++fr)
#pragma unroll
        for (int fc = 0; fc < 2; ++fc)
#pragma unroll
          for (int r = 0; r < 4; ++r) {
            const int pr = wr + (fr << 4) + (q4 << 2) + r;
            const int pc = wc + (fc << 4) + l16;
            float cv = bf2f(Blds[pc * PITCH + pr]);
            acc[fr][fc][r] -= 0.5f * cv * cv;
          }
    }
#pragma unroll
    for (int ks = 0; ks < 2; ++ks) {
      const int ko = (ks << 5) + (q4 << 3);
      short8 a0 = *reinterpret_cast<const short8*>(&Alds[(wr +      l16) * PITCH + ko]);
      short8 a1 = *reinterpret_cast<const short8*>(&Alds[(wr + 16 + l16) * PITCH + ko]);
      short8 b0 = *reinterpret_cast<const short8*>(&Blds[(wc +      l16) * PITCH + ko]);
      short8 b1 = *reinterpret_cast<const short8*>(&Blds[(wc + 16 + l16) * PITCH + ko]);
      acc[0][0] = __builtin_amdgcn_mfma_f32_16x16x32_bf16(a0, b0, acc[0][0], 0, 0, 0);
      acc[0][1] = __builtin_amdgcn_mfma_f32_16x16x32_bf16(a0, b1, acc[0][1], 0, 0, 0);
      acc[1][0] = __builtin_amdgcn_mfma_f32_16x16x32_bf16(a1, b0, acc[1][0], 0, 0, 0);
      acc[1][1] = __builtin_amdgcn_mfma_f32_16x16x32_bf16(a1, b1, acc[1][1], 0, 0, 0);
    }
    if (kb == 5) {
#pragma unroll
      for (int fr = 0; fr < 2; ++fr)
#pragma unroll
        for (int fc = 0; fc < 2; ++fc)
#pragma unroll
          for (int r = 0; r < 4; ++r) {
            const int idx = ((fr << 1) + fc) * 4 + r;
            float res = -2.0f * acc[fr][fc][r];
            float mi = m[idx];
            if (res <= mi) {
              s[idx] += __expf(res - mi);
            } else {
              s[idx] = s[idx] * __expf(mi - res) + 1.0f;
              m[idx] = res;
            }
            acc[fr][fc][r] = 0.0f;
          }
    }
    ++kb; if (kb == 6) { kb = 0; ++c; }
  }

  float local = 0.0f;
  const int* lb = Lab + (size_t)n * plane;
#pragma unroll
  for (int fr = 0; fr < 2; ++fr)
#pragma unroll
    for (int fc = 0; fc < 2; ++fc)
#pragma unroll
      for (int r = 0; r < 4; ++r) {
        const int idx = ((fr << 1) + fc) * 4 + r;
        const int pr = i0 + wr + (fr << 4) + (q4 << 2) + r;
        const int pc = j0 + wc + (fc << 4) + l16;
        float val = 1.0f / s[idx];
        float d = val * (float)lb[pr * Ww + pc];
        d = fminf(fmaxf(d, 1e-12f), 1e12f);
        local += d;
      }
#pragma unroll
  for (int off = 32; off > 0; off >>= 1) local += __shfl_down(local, off, 64);
  if (l == 0) red[w] = local;
  __syncthreads();
  if (t == 0) {
    float bs = (red[0] + red[1] + red[2] + red[3]) * (1.0f / 4718592.0f);
    atomicAdd(Out, bs);
  }
}

extern "C" void kernel_launch(void* const* d_in, const int* in_sizes, int n_in,
                              void* d_out, int out_size, void* d_ws, size_t ws_size,
                              hipStream_t stream) {
  const float* X   = (const float*)d_in[0];
  const float* Cen = (const float*)d_in[1];
  const int*   Lab = (const int*)d_in[2];
  float* Out = (float*)d_out;
  hipMemsetAsync(Out, 0, (size_t)out_size * sizeof(float), stream);

  const size_t ws_f2   = 2ull * Nn * Hh * Ww * sizeof(float2);  // 75.5 MB
  const size_t need    = ws_f2 + 1152 * sizeof(int);
  if (ws_size >= need && d_ws != nullptr) {
    float2* Ws = (float2*)d_ws;
    int* Flags = (int*)((char*)d_ws + ws_f2);
    hipMemsetAsync(Flags, 0, 1152 * sizeof(int), stream);
    hipLaunchKernelGGL(center_split, dim3(2 * Nn * 36), dim3(256), 0, stream,
                       X, Cen, Lab, Out, Ws, Flags);
  } else {
    hipLaunchKernelGGL(center_mono, dim3(Nn * 36), dim3(256), 0, stream,
                       X, Cen, Lab, Out);
  }
}